// Round 5
// baseline (348.527 us; speedup 1.0000x reference)
//
#include <hip/hip_runtime.h>
#include <hip/hip_bf16.h>
#include <hip/hip_cooperative_groups.h>

namespace cg = cooperative_groups;

// 1x1024x32x32: SE block + separable-gaussian spatial pool + 3x3 local softmax
// attention + 1x1 conv/BN/ReLU.  Single cooperative mega-kernel, 5 phases
// separated by grid.sync().  Grid 256 blocks x 256 threads = 1 block/CU.

typedef __attribute__((ext_vector_type(8))) short v8s;
typedef __attribute__((ext_vector_type(4))) float v4f;

__device__ __forceinline__ float sigmoidf_(float v) {
    return 1.f / (1.f + __expf(-v));
}
__device__ __forceinline__ unsigned short f2bf(float f) {
    unsigned u = __float_as_uint(f);
    u += 0x7fffu + ((u >> 16) & 1u);
    return (unsigned short)(u >> 16);
}
__device__ __forceinline__ float bf2f(unsigned short s) {
    return __uint_as_float(((unsigned)s) << 16);
}

union __align__(16) MegaSmem {
    struct { float ms[1024]; float y1[64]; float w2t[64 * 65]; } se;     // 21.0 KB
    struct { float T[64][65]; } pr;                                      // 16.6 KB
    struct { unsigned short As[64 * 72]; unsigned short Bs[64 * 72];
             float Gs[32][32]; } sp;                                     // 22.5 KB
    struct { unsigned short val[9216]; float part[9][4]; } at;           // 18.6 KB
    struct { unsigned short As[64 * 72]; unsigned short Bs[64 * 72]; } gm; // 18 KB
};

__global__ __launch_bounds__(256) void k_mega(
    const float* __restrict__ x, const float* __restrict__ w1,
    const float* __restrict__ b1, const float* __restrict__ w2,
    const float* __restrict__ b2, const float* __restrict__ W,
    const float* __restrict__ gamma, const float* __restrict__ beta,
    const float* __restrict__ mu, const float* __restrict__ var,
    float* __restrict__ mean, float* __restrict__ y2,
    unsigned short* __restrict__ Xsb, unsigned short* __restrict__ xrb,
    unsigned short* __restrict__ Bt, float* __restrict__ out) {
    __shared__ MegaSmem sm;
    cg::grid_group grid = cg::this_grid();
    int tid = threadIdx.x;
    int bx = blockIdx.x;
    int wv = tid >> 6, lane = tid & 63;

    // ---------- P1: per-channel mean (wave wv handles channel 4*bx+wv) ----------
    {
        int c = (bx << 2) + wv;
        const float* xp = x + (size_t)c * 1024;
        float4 a = *(const float4*)(xp + (lane << 2));
        float4 b4 = *(const float4*)(xp + 256 + (lane << 2));
        float4 c4 = *(const float4*)(xp + 512 + (lane << 2));
        float4 d4 = *(const float4*)(xp + 768 + (lane << 2));
        float s = a.x + a.y + a.z + a.w + b4.x + b4.y + b4.z + b4.w
                + c4.x + c4.y + c4.z + c4.w + d4.x + d4.y + d4.z + d4.w;
        #pragma unroll
        for (int o = 32; o; o >>= 1) s += __shfl_down(s, o);
        if (lane == 0) mean[c] = s * (1.f / 1024.f);
    }
    __threadfence();
    grid.sync();

    // ---------- P2: SE MLP (blocks 0..15, 64 outputs each) ----------
    if (bx < 16) {
        int c0 = bx << 6;
        #pragma unroll
        for (int i = 0; i < 4; ++i) sm.se.ms[tid + (i << 8)] = mean[tid + (i << 8)];
        #pragma unroll
        for (int i = 0; i < 16; ++i) {
            int idx = tid + (i << 8);
            sm.se.w2t[(idx >> 6) * 65 + (idx & 63)] = w2[(size_t)c0 * 64 + idx];
        }
        __syncthreads();
        for (int jj = 0; jj < 16; ++jj) {
            int j = wv * 16 + jj;
            float s = 0.f;
            #pragma unroll
            for (int kk = 0; kk < 4; ++kk) {
                float4 wv4 = *(const float4*)(w1 + (size_t)j * 1024 + kk * 256 + (lane << 2));
                float4 mv  = *(const float4*)&sm.se.ms[kk * 256 + (lane << 2)];
                s += wv4.x * mv.x + wv4.y * mv.y + wv4.z * mv.z + wv4.w * mv.w;
            }
            #pragma unroll
            for (int o = 32; o; o >>= 1) s += __shfl_down(s, o);
            if (lane == 0) sm.se.y1[j] = fmaxf(s + b1[j], 0.f);
        }
        __syncthreads();
        if (tid < 64) {
            float s = 0.f;
            #pragma unroll 16
            for (int jj = 0; jj < 64; ++jj) s += sm.se.y1[jj] * sm.se.w2t[tid * 65 + jj];
            y2[c0 + tid] = sigmoidf_(s + b2[c0 + tid]);
        }
    }
    __threadfence();
    grid.sync();

    // ---------- P3: prep  Xsb[c][hw]=bf16(x*y2); xrb[p][c]=bf16(sigmoid(x*y2)) ----------
    {
        int p0 = (bx & 15) << 6, c0 = (bx >> 4) << 6;
        #pragma unroll
        for (int i = 0; i < 4; ++i) {
            int idx = tid + (i << 8);
            int row = idx >> 4;
            int col = (idx & 15) << 2;
            float sc = y2[c0 + row];
            float4 v = *(const float4*)(x + (size_t)(c0 + row) * 1024 + p0 + col);
            uint2 pk;
            pk.x = (unsigned)f2bf(v.x * sc) | ((unsigned)f2bf(v.y * sc) << 16);
            pk.y = (unsigned)f2bf(v.z * sc) | ((unsigned)f2bf(v.w * sc) << 16);
            *(uint2*)(Xsb + (size_t)(c0 + row) * 1024 + p0 + col) = pk;
            sm.pr.T[col + 0][row] = sigmoidf_(v.x * sc);
            sm.pr.T[col + 1][row] = sigmoidf_(v.y * sc);
            sm.pr.T[col + 2][row] = sigmoidf_(v.z * sc);
            sm.pr.T[col + 3][row] = sigmoidf_(v.w * sc);
        }
        __syncthreads();
        #pragma unroll
        for (int i = 0; i < 4; ++i) {
            int idx = tid + (i << 8);
            int prow = idx >> 4;
            int cc = (idx & 15) << 2;
            uint2 pk;
            pk.x = (unsigned)f2bf(sm.pr.T[prow][cc + 0]) | ((unsigned)f2bf(sm.pr.T[prow][cc + 1]) << 16);
            pk.y = (unsigned)f2bf(sm.pr.T[prow][cc + 2]) | ((unsigned)f2bf(sm.pr.T[prow][cc + 3]) << 16);
            *(uint2*)(xrb + (size_t)(p0 + prow) * 1024 + c0 + cc) = pk;
        }
    }
    __threadfence();
    grid.sync();

    // ---------- P4a: spatial GEMM  Bt[p][1024+c] = sum_hw K2[p][hw]*Xsb[c][hw] ----------
    {
        {
            int row = tid >> 3, col0 = (tid & 7) << 2;
            float e[4], s = 0.f;
            #pragma unroll
            for (int j = 0; j < 4; ++j) {
                float d = (float)(row - (col0 + j));
                e[j] = __expf(-d * d / 4.5f);
                s += e[j];
            }
            s += __shfl_xor(s, 4, 8);
            s += __shfl_xor(s, 2, 8);
            s += __shfl_xor(s, 1, 8);
            float is = 1.f / s;
            #pragma unroll
            for (int j = 0; j < 4; ++j) sm.sp.Gs[row][col0 + j] = e[j] * is;
        }
        int wm = wv & 1, wn = wv >> 1;
        int m0 = (bx >> 4) << 6, n0 = (bx & 15) << 6;
        int col = lane & 15, quad = lane >> 4;
        int smi = tid >> 2;
        int sg = (tid & 3) * 2;
        int pm = m0 + smi;
        int rr = pm >> 5, qq = pm & 31;
        v4f acc[2][2];
        #pragma unroll
        for (int i = 0; i < 2; ++i)
            #pragma unroll
            for (int j = 0; j < 2; ++j) acc[i][j] = (v4f){0.f, 0.f, 0.f, 0.f};
        const float4* pb = (const float4*)(Xsb + (size_t)(n0 + smi) * 1024 + sg * 8);
        float4 rb0 = pb[0], rb1 = pb[1];
        for (int it = 0; it < 16; ++it) {
            __syncthreads();
            int k0 = it << 6;
            unsigned pk[8];
            #pragma unroll
            for (int jj = 0; jj < 8; ++jj) {
                int hw0 = k0 + sg * 8 + jj * 2;
                float v0 = sm.sp.Gs[rr][hw0 >> 5] * sm.sp.Gs[qq][hw0 & 31];
                float v1 = sm.sp.Gs[rr][(hw0 + 1) >> 5] * sm.sp.Gs[qq][(hw0 + 1) & 31];
                pk[jj] = (unsigned)f2bf(v0) | ((unsigned)f2bf(v1) << 16);
            }
            *(uint2*)&sm.sp.As[smi * 72 + sg * 8]      = *(uint2*)&pk[0];
            *(uint2*)&sm.sp.As[smi * 72 + sg * 8 + 4]  = *(uint2*)&pk[2];
            *(uint2*)&sm.sp.As[smi * 72 + sg * 8 + 8]  = *(uint2*)&pk[4];
            *(uint2*)&sm.sp.As[smi * 72 + sg * 8 + 12] = *(uint2*)&pk[6];
            *(float4*)&sm.sp.Bs[smi * 72 + sg * 8] = rb0;
            *(float4*)&sm.sp.Bs[smi * 72 + sg * 8 + 8] = rb1;
            __syncthreads();
            if (it + 1 < 16) {
                pb = (const float4*)(Xsb + (size_t)(n0 + smi) * 1024 + ((it + 1) << 6) + sg * 8);
                rb0 = pb[0]; rb1 = pb[1];
            }
            #pragma unroll
            for (int ks = 0; ks < 2; ++ks) {
                int kg = ks * 4 + quad;
                int rA = wm * 32 + col;
                int rB = wn * 32 + col;
                v8s a0 = *(const v8s*)&sm.sp.As[rA * 72 + kg * 8];
                v8s a1 = *(const v8s*)&sm.sp.As[(rA + 16) * 72 + kg * 8];
                v8s b0 = *(const v8s*)&sm.sp.Bs[rB * 72 + kg * 8];
                v8s b1 = *(const v8s*)&sm.sp.Bs[(rB + 16) * 72 + kg * 8];
                acc[0][0] = __builtin_amdgcn_mfma_f32_16x16x32_bf16(a0, b0, acc[0][0], 0, 0, 0);
                acc[0][1] = __builtin_amdgcn_mfma_f32_16x16x32_bf16(a0, b1, acc[0][1], 0, 0, 0);
                acc[1][0] = __builtin_amdgcn_mfma_f32_16x16x32_bf16(a1, b0, acc[1][0], 0, 0, 0);
                acc[1][1] = __builtin_amdgcn_mfma_f32_16x16x32_bf16(a1, b1, acc[1][1], 0, 0, 0);
            }
        }
        #pragma unroll
        for (int mi = 0; mi < 2; ++mi)
            #pragma unroll
            for (int ni = 0; ni < 2; ++ni) {
                int mb = m0 + wm * 32 + mi * 16 + quad * 4;
                int nn = n0 + wn * 32 + ni * 16 + col;
                #pragma unroll
                for (int r = 0; r < 4; ++r)
                    Bt[(size_t)(mb + r) * 2048 + 1024 + nn] = f2bf(acc[mi][ni][r]);
            }
    }

    // ---------- P4b: 3x3 local softmax attention, positions 4*bx..4*bx+3 ----------
    // val[f] with f = 9*cf+rem == 1024*q + c2 (reference reshape reinterpretation).
    for (int pi = 0; pi < 4; ++pi) {
        int p = (bx << 2) + pi;
        int h = p >> 5, w = p & 31;
        __syncthreads();          // previous LDS users done
        #pragma unroll
        for (int rem = 0; rem < 9; ++rem) {
            int dh = rem / 3 - 1, dw = rem % 3 - 1;
            bool ok = ((unsigned)(h + dh) < 32u) && ((unsigned)(w + dw) < 32u);
            const unsigned short* rp = xrb + (size_t)((h + dh) * 32 + (w + dw)) * 1024;
            #pragma unroll
            for (int j = 0; j < 4; ++j) {
                int cf = tid + (j << 8);
                sm.at.val[cf * 9 + rem] = ok ? rp[cf] : (unsigned short)0;
            }
        }
        __syncthreads();
        float ctr[4], vvq[9][4], lg[9];
        #pragma unroll
        for (int j = 0; j < 4; ++j) ctr[j] = bf2f(sm.at.val[(4 * tid + j) * 9 + 4]);
        #pragma unroll
        for (int q = 0; q < 9; ++q) {
            uint2 pk = *(const uint2*)&sm.at.val[q * 1024 + 4 * tid];
            vvq[q][0] = bf2f((unsigned short)(pk.x & 0xffffu));
            vvq[q][1] = bf2f((unsigned short)(pk.x >> 16));
            vvq[q][2] = bf2f((unsigned short)(pk.y & 0xffffu));
            vvq[q][3] = bf2f((unsigned short)(pk.y >> 16));
            lg[q] = ctr[0] * vvq[q][0] + ctr[1] * vvq[q][1]
                  + ctr[2] * vvq[q][2] + ctr[3] * vvq[q][3];
        }
        #pragma unroll
        for (int q = 0; q < 9; ++q) {
            float s = lg[q];
            #pragma unroll
            for (int o = 32; o; o >>= 1) s += __shfl_down(s, o);
            if (lane == 0) sm.at.part[q][wv] = s;
        }
        __syncthreads();
        float a9[9], mx = -3.4e38f;
        #pragma unroll
        for (int q = 0; q < 9; ++q) {
            a9[q] = sm.at.part[q][0] + sm.at.part[q][1] + sm.at.part[q][2] + sm.at.part[q][3];
            mx = fmaxf(mx, a9[q]);
        }
        float se = 0.f;
        #pragma unroll
        for (int q = 0; q < 9; ++q) { a9[q] = __expf(a9[q] - mx); se += a9[q]; }
        float inv = 1.f / se;
        float o4[4] = {0.f, 0.f, 0.f, 0.f};
        #pragma unroll
        for (int q = 0; q < 9; ++q) {
            float a = a9[q] * inv;
            #pragma unroll
            for (int j = 0; j < 4; ++j) o4[j] += a * vvq[q][j];
        }
        uint2 pk;
        pk.x = (unsigned)f2bf(o4[0]) | ((unsigned)f2bf(o4[1]) << 16);
        pk.y = (unsigned)f2bf(o4[2]) | ((unsigned)f2bf(o4[3]) << 16);
        *(uint2*)(Bt + (size_t)p * 2048 + 4 * tid) = pk;
    }
    __threadfence();
    grid.sync();

    // ---------- P5: main GEMM out = relu(BN(W . Bt^T)), W converted fp32->bf16 in staging ----------
    {
        int wm = wv & 1, wn = wv >> 1;
        int m0 = (bx >> 4) << 6, n0 = (bx & 15) << 6;
        int col = lane & 15, quad = lane >> 4;
        int smi = tid >> 2;
        int sg = (tid & 3) * 2;
        v4f acc[2][2];
        #pragma unroll
        for (int i = 0; i < 2; ++i)
            #pragma unroll
            for (int j = 0; j < 2; ++j) acc[i][j] = (v4f){0.f, 0.f, 0.f, 0.f};
        const float* pw = W + (size_t)(m0 + smi) * 2048 + sg * 8;
        const float4* pb = (const float4*)(Bt + (size_t)(n0 + smi) * 2048 + sg * 8);
        float4 wa0 = *(const float4*)pw, wa1 = *(const float4*)(pw + 4);
        float4 wa2 = *(const float4*)(pw + 8), wa3 = *(const float4*)(pw + 12);
        float4 rb0 = pb[0], rb1 = pb[1];
        for (int it = 0; it < 32; ++it) {
            __syncthreads();
            uint4 pk0, pk1;
            pk0.x = (unsigned)f2bf(wa0.x) | ((unsigned)f2bf(wa0.y) << 16);
            pk0.y = (unsigned)f2bf(wa0.z) | ((unsigned)f2bf(wa0.w) << 16);
            pk0.z = (unsigned)f2bf(wa1.x) | ((unsigned)f2bf(wa1.y) << 16);
            pk0.w = (unsigned)f2bf(wa1.z) | ((unsigned)f2bf(wa1.w) << 16);
            pk1.x = (unsigned)f2bf(wa2.x) | ((unsigned)f2bf(wa2.y) << 16);
            pk1.y = (unsigned)f2bf(wa2.z) | ((unsigned)f2bf(wa2.w) << 16);
            pk1.z = (unsigned)f2bf(wa3.x) | ((unsigned)f2bf(wa3.y) << 16);
            pk1.w = (unsigned)f2bf(wa3.z) | ((unsigned)f2bf(wa3.w) << 16);
            *(uint4*)&sm.gm.As[smi * 72 + sg * 8] = pk0;
            *(uint4*)&sm.gm.As[smi * 72 + sg * 8 + 8] = pk1;
            *(float4*)&sm.gm.Bs[smi * 72 + sg * 8] = rb0;
            *(float4*)&sm.gm.Bs[smi * 72 + sg * 8 + 8] = rb1;
            __syncthreads();
            if (it + 1 < 32) {
                int k0 = (it + 1) << 6;
                pw = W + (size_t)(m0 + smi) * 2048 + k0 + sg * 8;
                pb = (const float4*)(Bt + (size_t)(n0 + smi) * 2048 + k0 + sg * 8);
                wa0 = *(const float4*)pw; wa1 = *(const float4*)(pw + 4);
                wa2 = *(const float4*)(pw + 8); wa3 = *(const float4*)(pw + 12);
                rb0 = pb[0]; rb1 = pb[1];
            }
            #pragma unroll
            for (int ks = 0; ks < 2; ++ks) {
                int kg = ks * 4 + quad;
                int rA = wm * 32 + col;
                int rB = wn * 32 + col;
                v8s a0 = *(const v8s*)&sm.gm.As[rA * 72 + kg * 8];
                v8s a1 = *(const v8s*)&sm.gm.As[(rA + 16) * 72 + kg * 8];
                v8s b0 = *(const v8s*)&sm.gm.Bs[rB * 72 + kg * 8];
                v8s b1 = *(const v8s*)&sm.gm.Bs[(rB + 16) * 72 + kg * 8];
                acc[0][0] = __builtin_amdgcn_mfma_f32_16x16x32_bf16(a0, b0, acc[0][0], 0, 0, 0);
                acc[0][1] = __builtin_amdgcn_mfma_f32_16x16x32_bf16(a0, b1, acc[0][1], 0, 0, 0);
                acc[1][0] = __builtin_amdgcn_mfma_f32_16x16x32_bf16(a1, b0, acc[1][0], 0, 0, 0);
                acc[1][1] = __builtin_amdgcn_mfma_f32_16x16x32_bf16(a1, b1, acc[1][1], 0, 0, 0);
            }
        }
        #pragma unroll
        for (int mi = 0; mi < 2; ++mi)
            #pragma unroll
            for (int ni = 0; ni < 2; ++ni) {
                int mb = m0 + wm * 32 + mi * 16 + quad * 4;
                int nn = n0 + wn * 32 + ni * 16 + col;
                #pragma unroll
                for (int r = 0; r < 4; ++r) {
                    int mm = mb + r;
                    float iv = rsqrtf(var[mm] + 1e-5f);
                    float sc = iv * gamma[mm];
                    float sh = beta[mm] - mu[mm] * sc;
                    out[((size_t)mm << 10) + nn] = fmaxf(fmaf(acc[mi][ni][r], sc, sh), 0.f);
                }
            }
    }
}

extern "C" void kernel_launch(void* const* d_in, const int* in_sizes, int n_in,
                              void* d_out, int out_size, void* d_ws, size_t ws_size,
                              hipStream_t stream) {
    const float* x     = (const float*)d_in[0];
    const float* w1    = (const float*)d_in[1];
    const float* b1    = (const float*)d_in[2];
    const float* w2    = (const float*)d_in[3];
    const float* b2    = (const float*)d_in[4];
    const float* cw    = (const float*)d_in[5];
    const float* gamma = (const float*)d_in[6];
    const float* beta  = (const float*)d_in[7];
    const float* mu    = (const float*)d_in[8];
    const float* var   = (const float*)d_in[9];
    float* wsf = (float*)d_ws;
    unsigned short* Bt  = (unsigned short*)(wsf + (1 << 20));             // 4 MB [1024][2048]
    unsigned short* Xsb = (unsigned short*)(wsf + (2 << 20));             // 2 MB [c][hw]
    unsigned short* xrb = (unsigned short*)(wsf + (2 << 20) + (1 << 19)); // 2 MB [p][c]
    float* mean = wsf + (3 << 20);
    float* y2   = mean + 1024;
    float* out  = (float*)d_out;

    void* args[] = {
        (void*)&x, (void*)&w1, (void*)&b1, (void*)&w2, (void*)&b2, (void*)&cw,
        (void*)&gamma, (void*)&beta, (void*)&mu, (void*)&var,
        (void*)&mean, (void*)&y2, (void*)&Xsb, (void*)&xrb, (void*)&Bt, (void*)&out
    };
    hipLaunchCooperativeKernel((const void*)k_mega, dim3(256), dim3(256),
                               args, 0, stream);
}

// Round 6
// 159.255 us; speedup vs baseline: 2.1885x; 2.1885x over previous
//
#include <hip/hip_runtime.h>
#include <hip/hip_bf16.h>

// 1x1024x32x32: SE block + separable-gaussian spatial pool + 3x3 local softmax
// attention + 1x1 conv/BN/ReLU.  Round 6: 4 launches.
//   k_A      : per-channel mean + xb=bf16(x) + Wb=bf16(W)      (all independent)
//   k_se     : SE MLP -> y2
//   k_spattn : blocks 0..255   spatial GEMM on raw xb, *y2 in epilogue
//              blocks 256..1279 attention with INLINE fp32 sigmoid (no xrb)
//   k_main   : bf16 MFMA GEMM (double-buffered LDS) + BN + ReLU
// NOTE: cooperative grid.sync() measured ~60us/sync on this 8-XCD part (round 5)
// — multi-kernel structure is strictly better.

typedef __attribute__((ext_vector_type(8))) short v8s;
typedef __attribute__((ext_vector_type(4))) float v4f;

__device__ __forceinline__ float sigmoidf_(float v) {
    return 1.f / (1.f + __expf(-v));
}
__device__ __forceinline__ unsigned short f2bf(float f) {
    unsigned u = __float_as_uint(f);
    u += 0x7fffu + ((u >> 16) & 1u);
    return (unsigned short)(u >> 16);
}

// ---------------- K1: mean + xb pack + Wb pack ----------------
__global__ __launch_bounds__(256) void k_A(const float* __restrict__ x,
                                           const float* __restrict__ W,
                                           float* __restrict__ mean,
                                           unsigned short* __restrict__ xb,
                                           unsigned short* __restrict__ Wb) {
    int tid = threadIdx.x, bx = blockIdx.x;
    int wv = tid >> 6, lane = tid & 63;
    // W pack: 2M elements, 8 coalesced chunks of 256K (block covers 1024/chunk)
    #pragma unroll
    for (int k = 0; k < 8; ++k) {
        int e = (k << 18) + (bx << 10) + (tid << 2);
        float4 v = *(const float4*)(W + e);
        uint2 pk;
        pk.x = (unsigned)f2bf(v.x) | ((unsigned)f2bf(v.y) << 16);
        pk.y = (unsigned)f2bf(v.z) | ((unsigned)f2bf(v.w) << 16);
        *(uint2*)(Wb + e) = pk;
    }
    // channel c = 4*bx+wv: mean + bf16 pack of x
    int c = (bx << 2) + wv;
    const float* xp = x + (size_t)c * 1024;
    float s = 0.f;
    #pragma unroll
    for (int j = 0; j < 4; ++j) {
        int o = (j << 8) + (lane << 2);
        float4 v = *(const float4*)(xp + o);
        uint2 pk;
        pk.x = (unsigned)f2bf(v.x) | ((unsigned)f2bf(v.y) << 16);
        pk.y = (unsigned)f2bf(v.z) | ((unsigned)f2bf(v.w) << 16);
        *(uint2*)(xb + (size_t)c * 1024 + o) = pk;
        s += v.x + v.y + v.z + v.w;
    }
    #pragma unroll
    for (int o = 32; o; o >>= 1) s += __shfl_down(s, o);
    if (lane == 0) mean[c] = s * (1.f / 1024.f);
}

// ---------------- K2: SE MLP, 16 blocks x 1024 threads ----------------
__global__ __launch_bounds__(1024) void k_se(const float* __restrict__ mean,
                                             const float* __restrict__ w1,
                                             const float* __restrict__ b1,
                                             const float* __restrict__ w2,
                                             const float* __restrict__ b2,
                                             float* __restrict__ y2) {
    __shared__ float ms[1024];
    __shared__ float y1[64];
    __shared__ float w2t[64 * 65];
    int tid = threadIdx.x;
    int c0 = blockIdx.x << 6;
    ms[tid] = mean[tid];
    #pragma unroll
    for (int i = 0; i < 4; ++i) {
        int idx = tid + (i << 10);
        w2t[(idx >> 6) * 65 + (idx & 63)] = w2[(size_t)c0 * 64 + idx];
    }
    __syncthreads();
    int wv = tid >> 6, lane = tid & 63;
    #pragma unroll
    for (int jj = 0; jj < 4; ++jj) {
        int j = (wv << 2) + jj;
        float s = 0.f;
        #pragma unroll
        for (int kk = 0; kk < 4; ++kk) {
            float4 wv4 = *(const float4*)(w1 + (size_t)j * 1024 + kk * 256 + (lane << 2));
            float4 mv  = *(const float4*)&ms[kk * 256 + (lane << 2)];
            s += wv4.x * mv.x + wv4.y * mv.y + wv4.z * mv.z + wv4.w * mv.w;
        }
        #pragma unroll
        for (int o = 32; o; o >>= 1) s += __shfl_down(s, o);
        if (lane == 0) y1[j] = fmaxf(s + b1[j], 0.f);
    }
    __syncthreads();
    int o = tid >> 4, l = tid & 15;
    float s = 0.f;
    #pragma unroll
    for (int jj = 0; jj < 4; ++jj) s += y1[l + (jj << 4)] * w2t[o * 65 + l + (jj << 4)];
    #pragma unroll
    for (int o2 = 8; o2; o2 >>= 1) s += __shfl_down(s, o2, 16);
    if (l == 0) y2[c0 + o] = sigmoidf_(s + b2[c0 + o]);
}

// ---------------- K3: fused spatial GEMM + attention ----------------
union __align__(16) SMem {
    struct { unsigned short As[64 * 72]; unsigned short Bs[64 * 72]; float Gs[32][32]; } sp;
    struct { float val[9216]; float part[9][4]; } at;   // 36.1 KB
};

__global__ __launch_bounds__(256) void k_spattn(const float* __restrict__ x,
                                                const unsigned short* __restrict__ xb,
                                                const float* __restrict__ y2,
                                                unsigned short* __restrict__ Bt) {
    __shared__ SMem sm;
    int tid = threadIdx.x;
    int bx = blockIdx.x;
    int wv = tid >> 6, lane = tid & 63;
    if (bx < 256) {
        // spatial GEMM on RAW xb: Bt[p][1024+c] = y2[c] * sum_hw K2[p][hw]*xb[c][hw]
        {
            int row = tid >> 3, col0 = (tid & 7) << 2;
            float e[4], s = 0.f;
            #pragma unroll
            for (int j = 0; j < 4; ++j) {
                float d = (float)(row - (col0 + j));
                e[j] = __expf(-d * d / 4.5f);
                s += e[j];
            }
            s += __shfl_xor(s, 4, 8);
            s += __shfl_xor(s, 2, 8);
            s += __shfl_xor(s, 1, 8);
            float is = 1.f / s;
            #pragma unroll
            for (int j = 0; j < 4; ++j) sm.sp.Gs[row][col0 + j] = e[j] * is;
        }
        int wm = wv & 1, wn = wv >> 1;
        int m0 = (bx >> 4) << 6, n0 = (bx & 15) << 6;
        int col = lane & 15, quad = lane >> 4;
        int smi = tid >> 2;
        int sg = (tid & 3) * 2;
        int pm = m0 + smi;
        int rr = pm >> 5, qq = pm & 31;
        v4f acc[2][2];
        #pragma unroll
        for (int i = 0; i < 2; ++i)
            #pragma unroll
            for (int j = 0; j < 2; ++j) acc[i][j] = (v4f){0.f, 0.f, 0.f, 0.f};
        const float4* pb = (const float4*)(xb + (size_t)(n0 + smi) * 1024 + sg * 8);
        float4 rb0 = pb[0], rb1 = pb[1];
        for (int it = 0; it < 16; ++it) {
            __syncthreads();
            int k0 = it << 6;
            unsigned pk[8];
            #pragma unroll
            for (int jj = 0; jj < 8; ++jj) {
                int hw0 = k0 + sg * 8 + jj * 2;
                float v0 = sm.sp.Gs[rr][hw0 >> 5] * sm.sp.Gs[qq][hw0 & 31];
                float v1 = sm.sp.Gs[rr][(hw0 + 1) >> 5] * sm.sp.Gs[qq][(hw0 + 1) & 31];
                pk[jj] = (unsigned)f2bf(v0) | ((unsigned)f2bf(v1) << 16);
            }
            *(uint2*)&sm.sp.As[smi * 72 + sg * 8]      = *(uint2*)&pk[0];
            *(uint2*)&sm.sp.As[smi * 72 + sg * 8 + 4]  = *(uint2*)&pk[2];
            *(uint2*)&sm.sp.As[smi * 72 + sg * 8 + 8]  = *(uint2*)&pk[4];
            *(uint2*)&sm.sp.As[smi * 72 + sg * 8 + 12] = *(uint2*)&pk[6];
            *(float4*)&sm.sp.Bs[smi * 72 + sg * 8] = rb0;
            *(float4*)&sm.sp.Bs[smi * 72 + sg * 8 + 8] = rb1;
            __syncthreads();
            if (it + 1 < 16) {
                pb = (const float4*)(xb + (size_t)(n0 + smi) * 1024 + ((it + 1) << 6) + sg * 8);
                rb0 = pb[0]; rb1 = pb[1];
            }
            #pragma unroll
            for (int ks = 0; ks < 2; ++ks) {
                int kg = ks * 4 + quad;
                int rA = wm * 32 + col;
                int rB = wn * 32 + col;
                v8s a0 = *(const v8s*)&sm.sp.As[rA * 72 + kg * 8];
                v8s a1 = *(const v8s*)&sm.sp.As[(rA + 16) * 72 + kg * 8];
                v8s b0 = *(const v8s*)&sm.sp.Bs[rB * 72 + kg * 8];
                v8s b1 = *(const v8s*)&sm.sp.Bs[(rB + 16) * 72 + kg * 8];
                acc[0][0] = __builtin_amdgcn_mfma_f32_16x16x32_bf16(a0, b0, acc[0][0], 0, 0, 0);
                acc[0][1] = __builtin_amdgcn_mfma_f32_16x16x32_bf16(a0, b1, acc[0][1], 0, 0, 0);
                acc[1][0] = __builtin_amdgcn_mfma_f32_16x16x32_bf16(a1, b0, acc[1][0], 0, 0, 0);
                acc[1][1] = __builtin_amdgcn_mfma_f32_16x16x32_bf16(a1, b1, acc[1][1], 0, 0, 0);
            }
        }
        #pragma unroll
        for (int mi = 0; mi < 2; ++mi)
            #pragma unroll
            for (int ni = 0; ni < 2; ++ni) {
                int mb = m0 + wm * 32 + mi * 16 + quad * 4;
                int nn = n0 + wn * 32 + ni * 16 + col;
                float yv = y2[nn];               // SE scale commuted past the pool
                #pragma unroll
                for (int r = 0; r < 4; ++r)
                    Bt[(size_t)(mb + r) * 2048 + 1024 + nn] = f2bf(acc[mi][ni][r] * yv);
            }
    } else {
        // attention, position p = bx-256; sigmoid computed inline in fp32.
        // val[f] with f = 9*cf+rem == 1024*q + c2 (reference reshape reinterpretation).
        int p = bx - 256;
        int h = p >> 5, w = p & 31;
        float yv[4];
        #pragma unroll
        for (int j = 0; j < 4; ++j) yv[j] = y2[tid + (j << 8)];
        #pragma unroll
        for (int rem = 0; rem < 9; ++rem) {
            int dh = rem / 3 - 1, dw = rem % 3 - 1;
            bool ok = ((unsigned)(h + dh) < 32u) && ((unsigned)(w + dw) < 32u);
            int pp = (h + dh) * 32 + (w + dw);
            #pragma unroll
            for (int j = 0; j < 4; ++j) {
                int cf = tid + (j << 8);
                float v = 0.f;
                if (ok) v = sigmoidf_(x[(size_t)cf * 1024 + pp] * yv[j]);
                sm.at.val[cf * 9 + rem] = v;     // 0 for OOB (pad-before-sigmoid)
            }
        }
        __syncthreads();
        float ctr[4], vvq[9][4], lg[9];
        #pragma unroll
        for (int j = 0; j < 4; ++j) ctr[j] = sm.at.val[(4 * tid + j) * 9 + 4];
        #pragma unroll
        for (int q = 0; q < 9; ++q) {
            float4 v4 = *(const float4*)&sm.at.val[(q << 10) + 4 * tid];
            vvq[q][0] = v4.x; vvq[q][1] = v4.y; vvq[q][2] = v4.z; vvq[q][3] = v4.w;
            lg[q] = ctr[0] * v4.x + ctr[1] * v4.y + ctr[2] * v4.z + ctr[3] * v4.w;
        }
        #pragma unroll
        for (int q = 0; q < 9; ++q) {
            float s = lg[q];
            #pragma unroll
            for (int o = 32; o; o >>= 1) s += __shfl_down(s, o);
            if (lane == 0) sm.at.part[q][wv] = s;
        }
        __syncthreads();
        float a9[9], mx = -3.4e38f;
        #pragma unroll
        for (int q = 0; q < 9; ++q) {
            a9[q] = sm.at.part[q][0] + sm.at.part[q][1] + sm.at.part[q][2] + sm.at.part[q][3];
            mx = fmaxf(mx, a9[q]);
        }
        float se = 0.f;
        #pragma unroll
        for (int q = 0; q < 9; ++q) { a9[q] = __expf(a9[q] - mx); se += a9[q]; }
        float inv = 1.f / se;
        float o4[4] = {0.f, 0.f, 0.f, 0.f};
        #pragma unroll
        for (int q = 0; q < 9; ++q) {
            float a = a9[q] * inv;
            #pragma unroll
            for (int j = 0; j < 4; ++j) o4[j] += a * vvq[q][j];
        }
        uint2 pk;
        pk.x = (unsigned)f2bf(o4[0]) | ((unsigned)f2bf(o4[1]) << 16);
        pk.y = (unsigned)f2bf(o4[2]) | ((unsigned)f2bf(o4[3]) << 16);
        *(uint2*)(Bt + (size_t)p * 2048 + 4 * tid) = pk;
    }
}

// ---------------- K4: main GEMM, double-buffered LDS, BN + ReLU ----------------
__global__ __launch_bounds__(256) void k_main(
    const unsigned short* __restrict__ A, const unsigned short* __restrict__ B,
    float* __restrict__ outF,
    const float* __restrict__ gamma, const float* __restrict__ beta,
    const float* __restrict__ mu, const float* __restrict__ var) {
    __shared__ unsigned short As[2][64 * 72];
    __shared__ unsigned short Bs[2][64 * 72];
    const int K = 2048;
    int tid = threadIdx.x;
    int wv = tid >> 6, lane = tid & 63;
    int wm = wv & 1, wn = wv >> 1;
    int m0 = blockIdx.y << 6, n0 = blockIdx.x << 6;
    int col = lane & 15, quad = lane >> 4;
    int sm = tid >> 2;
    int sg = (tid & 3) * 2;
    v4f acc[2][2];
    #pragma unroll
    for (int i = 0; i < 2; ++i)
        #pragma unroll
        for (int j = 0; j < 2; ++j) acc[i][j] = (v4f){0.f, 0.f, 0.f, 0.f};

    const float4* pa = (const float4*)(A + (size_t)(m0 + sm) * K + sg * 8);
    const float4* pb = (const float4*)(B + (size_t)(n0 + sm) * K + sg * 8);
    float4 ra0 = pa[0], ra1 = pa[1], rb0 = pb[0], rb1 = pb[1];
    *(float4*)&As[0][sm * 72 + sg * 8] = ra0;
    *(float4*)&As[0][sm * 72 + sg * 8 + 8] = ra1;
    *(float4*)&Bs[0][sm * 72 + sg * 8] = rb0;
    *(float4*)&Bs[0][sm * 72 + sg * 8 + 8] = rb1;
    for (int it = 0; it < 32; ++it) {
        __syncthreads();
        int cur = it & 1;
        if (it + 1 < 32) {
            int k0 = (it + 1) << 6;
            pa = (const float4*)(A + (size_t)(m0 + sm) * K + k0 + sg * 8);
            pb = (const float4*)(B + (size_t)(n0 + sm) * K + k0 + sg * 8);
            ra0 = pa[0]; ra1 = pa[1];
            rb0 = pb[0]; rb1 = pb[1];
        }
        #pragma unroll
        for (int ks = 0; ks < 2; ++ks) {
            int kg = ks * 4 + quad;
            int rA = wm * 32 + col;
            int rB = wn * 32 + col;
            v8s a0 = *(const v8s*)&As[cur][rA * 72 + kg * 8];
            v8s a1 = *(const v8s*)&As[cur][(rA + 16) * 72 + kg * 8];
            v8s b0 = *(const v8s*)&Bs[cur][rB * 72 + kg * 8];
            v8s b1 = *(const v8s*)&Bs[cur][(rB + 16) * 72 + kg * 8];
            acc[0][0] = __builtin_amdgcn_mfma_f32_16x16x32_bf16(a0, b0, acc[0][0], 0, 0, 0);
            acc[0][1] = __builtin_amdgcn_mfma_f32_16x16x32_bf16(a0, b1, acc[0][1], 0, 0, 0);
            acc[1][0] = __builtin_amdgcn_mfma_f32_16x16x32_bf16(a1, b0, acc[1][0], 0, 0, 0);
            acc[1][1] = __builtin_amdgcn_mfma_f32_16x16x32_bf16(a1, b1, acc[1][1], 0, 0, 0);
        }
        if (it + 1 < 32) {
            int nxt = cur ^ 1;
            *(float4*)&As[nxt][sm * 72 + sg * 8] = ra0;
            *(float4*)&As[nxt][sm * 72 + sg * 8 + 8] = ra1;
            *(float4*)&Bs[nxt][sm * 72 + sg * 8] = rb0;
            *(float4*)&Bs[nxt][sm * 72 + sg * 8 + 8] = rb1;
        }
    }
    #pragma unroll
    for (int mi = 0; mi < 2; ++mi)
        #pragma unroll
        for (int ni = 0; ni < 2; ++ni) {
            int mb = m0 + wm * 32 + mi * 16 + quad * 4;
            int nn = n0 + wn * 32 + ni * 16 + col;
            #pragma unroll
            for (int r = 0; r < 4; ++r) {
                int mm = mb + r;
                float iv = rsqrtf(var[mm] + 1e-5f);
                float sc = iv * gamma[mm];
                float sh = beta[mm] - mu[mm] * sc;
                outF[((size_t)mm << 10) + nn] = fmaxf(fmaf(acc[mi][ni][r], sc, sh), 0.f);
            }
        }
}

extern "C" void kernel_launch(void* const* d_in, const int* in_sizes, int n_in,
                              void* d_out, int out_size, void* d_ws, size_t ws_size,
                              hipStream_t stream) {
    const float* x     = (const float*)d_in[0];
    const float* w1    = (const float*)d_in[1];
    const float* b1    = (const float*)d_in[2];
    const float* w2    = (const float*)d_in[3];
    const float* b2    = (const float*)d_in[4];
    const float* cw    = (const float*)d_in[5];
    const float* gamma = (const float*)d_in[6];
    const float* beta  = (const float*)d_in[7];
    const float* mu    = (const float*)d_in[8];
    const float* var   = (const float*)d_in[9];
    float* wsf = (float*)d_ws;
    unsigned short* Wb = (unsigned short*)wsf;                 // 4 MB [1024][2048]
    unsigned short* Bt = (unsigned short*)(wsf + (1 << 20));   // 4 MB [1024][2048]
    unsigned short* xb = (unsigned short*)(wsf + (2 << 20));   // 2 MB [c][hw]
    float* mean = wsf + (3 << 20);
    float* y2   = mean + 1024;
    float* out  = (float*)d_out;

    dim3 g16(16, 16);
    k_A     <<<256, 256, 0, stream>>>(x, cw, mean, xb, Wb);
    k_se    <<<16, 1024, 0, stream>>>(mean, w1, b1, w2, b2, y2);
    k_spattn<<<1280, 256, 0, stream>>>(x, xb, y2, Bt);
    k_main  <<<g16, 256, 0, stream>>>(Wb, Bt, out, gamma, beta, mu, var);
}

// Round 7
// 131.026 us; speedup vs baseline: 2.6600x; 1.2154x over previous
//
#include <hip/hip_runtime.h>
#include <hip/hip_bf16.h>

// 1x1024x32x32: SE block + separable-gaussian spatial pool + 3x3 local softmax
// attention + 1x1 conv/BN/ReLU.  Round 7: 5 launches.
//   k_A     : per-channel mean + Wb=bf16(W)
//   k_se    : SE MLP -> y2
//   k_prep  : xrb[p][c] = bf16(sigmoid(x*y2[c]))   (transpose via LDS)
//   k_spattn: blocks 0..255   spatial GEMM staging B from fp32 x (inline bf16
//             convert), *y2 in epilogue (SE scale commutes past the pool)
//             blocks 256..1279 attention on coalesced xrb rows (bf16 LDS)
//   k_main  : bf16 MFMA GEMM (double-buffered LDS) + BN + ReLU
// Lessons pinned: grid.sync ~60us/sync on 8 XCDs (r5) — never cooperative.
//                 inline-sigmoid attention = 9.4M scattered 4B loads (r6) —
//                 always transpose once, then read rows.

typedef __attribute__((ext_vector_type(8))) short v8s;
typedef __attribute__((ext_vector_type(4))) float v4f;

__device__ __forceinline__ float sigmoidf_(float v) {
    return 1.f / (1.f + __expf(-v));
}
__device__ __forceinline__ unsigned short f2bf(float f) {
    unsigned u = __float_as_uint(f);
    u += 0x7fffu + ((u >> 16) & 1u);
    return (unsigned short)(u >> 16);
}
__device__ __forceinline__ float bf2f(unsigned short s) {
    return __uint_as_float(((unsigned)s) << 16);
}

// ---------------- K1: mean + Wb pack ----------------
__global__ __launch_bounds__(256) void k_A(const float* __restrict__ x,
                                           const float* __restrict__ W,
                                           float* __restrict__ mean,
                                           unsigned short* __restrict__ Wb) {
    int tid = threadIdx.x, bx = blockIdx.x;
    int wv = tid >> 6, lane = tid & 63;
    // W pack: 2M elements, 8 coalesced chunks
    #pragma unroll
    for (int k = 0; k < 8; ++k) {
        int e = (k << 18) + (bx << 10) + (tid << 2);
        float4 v = *(const float4*)(W + e);
        uint2 pk;
        pk.x = (unsigned)f2bf(v.x) | ((unsigned)f2bf(v.y) << 16);
        pk.y = (unsigned)f2bf(v.z) | ((unsigned)f2bf(v.w) << 16);
        *(uint2*)(Wb + e) = pk;
    }
    // channel c = 4*bx+wv: mean
    int c = (bx << 2) + wv;
    const float* xp = x + (size_t)c * 1024;
    float s = 0.f;
    #pragma unroll
    for (int j = 0; j < 4; ++j) {
        float4 v = *(const float4*)(xp + (j << 8) + (lane << 2));
        s += v.x + v.y + v.z + v.w;
    }
    #pragma unroll
    for (int o = 32; o; o >>= 1) s += __shfl_down(s, o);
    if (lane == 0) mean[c] = s * (1.f / 1024.f);
}

// ---------------- K2: SE MLP, 16 blocks x 1024 threads ----------------
__global__ __launch_bounds__(1024) void k_se(const float* __restrict__ mean,
                                             const float* __restrict__ w1,
                                             const float* __restrict__ b1,
                                             const float* __restrict__ w2,
                                             const float* __restrict__ b2,
                                             float* __restrict__ y2) {
    __shared__ float ms[1024];
    __shared__ float y1[64];
    __shared__ float w2t[64 * 65];
    int tid = threadIdx.x;
    int c0 = blockIdx.x << 6;
    ms[tid] = mean[tid];
    #pragma unroll
    for (int i = 0; i < 4; ++i) {
        int idx = tid + (i << 10);
        w2t[(idx >> 6) * 65 + (idx & 63)] = w2[(size_t)c0 * 64 + idx];
    }
    __syncthreads();
    int wv = tid >> 6, lane = tid & 63;
    #pragma unroll
    for (int jj = 0; jj < 4; ++jj) {
        int j = (wv << 2) + jj;
        float s = 0.f;
        #pragma unroll
        for (int kk = 0; kk < 4; ++kk) {
            float4 wv4 = *(const float4*)(w1 + (size_t)j * 1024 + kk * 256 + (lane << 2));
            float4 mv  = *(const float4*)&ms[kk * 256 + (lane << 2)];
            s += wv4.x * mv.x + wv4.y * mv.y + wv4.z * mv.z + wv4.w * mv.w;
        }
        #pragma unroll
        for (int o = 32; o; o >>= 1) s += __shfl_down(s, o);
        if (lane == 0) y1[j] = fmaxf(s + b1[j], 0.f);
    }
    __syncthreads();
    int o = tid >> 4, l = tid & 15;
    float s = 0.f;
    #pragma unroll
    for (int jj = 0; jj < 4; ++jj) s += y1[l + (jj << 4)] * w2t[o * 65 + l + (jj << 4)];
    #pragma unroll
    for (int o2 = 8; o2; o2 >>= 1) s += __shfl_down(s, o2, 16);
    if (l == 0) y2[c0 + o] = sigmoidf_(s + b2[c0 + o]);
}

// ---------------- K3: xrb[p][c] = bf16(sigmoid(x[c][p]*y2[c])) ----------------
__global__ __launch_bounds__(256) void k_prep(const float* __restrict__ x,
                                              const float* __restrict__ y2,
                                              unsigned short* __restrict__ xrb) {
    __shared__ float T[64][65];
    int tid = threadIdx.x;
    int p0 = blockIdx.x << 6, c0 = blockIdx.y << 6;
    #pragma unroll
    for (int i = 0; i < 4; ++i) {
        int idx = tid + (i << 8);
        int row = idx >> 4;              // channel offset 0..63
        int col = (idx & 15) << 2;       // p offset
        float sc = y2[c0 + row];
        float4 v = *(const float4*)(x + (size_t)(c0 + row) * 1024 + p0 + col);
        T[col + 0][row] = sigmoidf_(v.x * sc);
        T[col + 1][row] = sigmoidf_(v.y * sc);
        T[col + 2][row] = sigmoidf_(v.z * sc);
        T[col + 3][row] = sigmoidf_(v.w * sc);
    }
    __syncthreads();
    #pragma unroll
    for (int i = 0; i < 4; ++i) {
        int idx = tid + (i << 8);
        int prow = idx >> 4;
        int cc = (idx & 15) << 2;
        uint2 pk;
        pk.x = (unsigned)f2bf(T[prow][cc + 0]) | ((unsigned)f2bf(T[prow][cc + 1]) << 16);
        pk.y = (unsigned)f2bf(T[prow][cc + 2]) | ((unsigned)f2bf(T[prow][cc + 3]) << 16);
        *(uint2*)(xrb + (size_t)(p0 + prow) * 1024 + c0 + cc) = pk;
    }
}

// ---------------- K4: fused spatial GEMM + attention ----------------
union __align__(16) SMem {
    struct { unsigned short As[64 * 72]; unsigned short Bs[64 * 72]; float Gs[32][32]; } sp; // 22.5 KB
    struct { unsigned short val[9216]; float part[9][4]; } at;                               // 18.6 KB
};

__global__ __launch_bounds__(256) void k_spattn(const float* __restrict__ x,
                                                const unsigned short* __restrict__ xrb,
                                                const float* __restrict__ y2,
                                                unsigned short* __restrict__ Bt) {
    __shared__ SMem sm;
    int tid = threadIdx.x;
    int bx = blockIdx.x;
    int wv = tid >> 6, lane = tid & 63;
    if (bx < 256) {
        // spatial GEMM: Bt[p][1024+c] = y2[c] * sum_hw K2[p][hw]*bf16(x[c][hw])
        {
            int row = tid >> 3, col0 = (tid & 7) << 2;
            float e[4], s = 0.f;
            #pragma unroll
            for (int j = 0; j < 4; ++j) {
                float d = (float)(row - (col0 + j));
                e[j] = __expf(-d * d / 4.5f);
                s += e[j];
            }
            s += __shfl_xor(s, 4, 8);
            s += __shfl_xor(s, 2, 8);
            s += __shfl_xor(s, 1, 8);
            float is = 1.f / s;
            #pragma unroll
            for (int j = 0; j < 4; ++j) sm.sp.Gs[row][col0 + j] = e[j] * is;
        }
        int wm = wv & 1, wn = wv >> 1;
        int m0 = (bx >> 4) << 6, n0 = (bx & 15) << 6;
        int col = lane & 15, quad = lane >> 4;
        int smi = tid >> 2;
        int sg = (tid & 3) * 2;
        int pm = m0 + smi;
        int rr = pm >> 5, qq = pm & 31;
        v4f acc[2][2];
        #pragma unroll
        for (int i = 0; i < 2; ++i)
            #pragma unroll
            for (int j = 0; j < 2; ++j) acc[i][j] = (v4f){0.f, 0.f, 0.f, 0.f};
        const float4* pb = (const float4*)(x + (size_t)(n0 + smi) * 1024 + sg * 8);
        float4 xa0 = pb[0], xa1 = pb[1], xa2 = pb[2], xa3 = pb[3];
        for (int it = 0; it < 16; ++it) {
            __syncthreads();
            int k0 = it << 6;
            unsigned pk[8];
            #pragma unroll
            for (int jj = 0; jj < 8; ++jj) {
                int hw0 = k0 + sg * 8 + jj * 2;
                float v0 = sm.sp.Gs[rr][hw0 >> 5] * sm.sp.Gs[qq][hw0 & 31];
                float v1 = sm.sp.Gs[rr][(hw0 + 1) >> 5] * sm.sp.Gs[qq][(hw0 + 1) & 31];
                pk[jj] = (unsigned)f2bf(v0) | ((unsigned)f2bf(v1) << 16);
            }
            *(uint2*)&sm.sp.As[smi * 72 + sg * 8]      = *(uint2*)&pk[0];
            *(uint2*)&sm.sp.As[smi * 72 + sg * 8 + 4]  = *(uint2*)&pk[2];
            *(uint2*)&sm.sp.As[smi * 72 + sg * 8 + 8]  = *(uint2*)&pk[4];
            *(uint2*)&sm.sp.As[smi * 72 + sg * 8 + 12] = *(uint2*)&pk[6];
            uint4 pkb0, pkb1;
            pkb0.x = (unsigned)f2bf(xa0.x) | ((unsigned)f2bf(xa0.y) << 16);
            pkb0.y = (unsigned)f2bf(xa0.z) | ((unsigned)f2bf(xa0.w) << 16);
            pkb0.z = (unsigned)f2bf(xa1.x) | ((unsigned)f2bf(xa1.y) << 16);
            pkb0.w = (unsigned)f2bf(xa1.z) | ((unsigned)f2bf(xa1.w) << 16);
            pkb1.x = (unsigned)f2bf(xa2.x) | ((unsigned)f2bf(xa2.y) << 16);
            pkb1.y = (unsigned)f2bf(xa2.z) | ((unsigned)f2bf(xa2.w) << 16);
            pkb1.z = (unsigned)f2bf(xa3.x) | ((unsigned)f2bf(xa3.y) << 16);
            pkb1.w = (unsigned)f2bf(xa3.z) | ((unsigned)f2bf(xa3.w) << 16);
            *(uint4*)&sm.sp.Bs[smi * 72 + sg * 8] = pkb0;
            *(uint4*)&sm.sp.Bs[smi * 72 + sg * 8 + 8] = pkb1;
            __syncthreads();
            if (it + 1 < 16) {
                pb = (const float4*)(x + (size_t)(n0 + smi) * 1024 + ((it + 1) << 6) + sg * 8);
                xa0 = pb[0]; xa1 = pb[1]; xa2 = pb[2]; xa3 = pb[3];
            }
            #pragma unroll
            for (int ks = 0; ks < 2; ++ks) {
                int kg = ks * 4 + quad;
                int rA = wm * 32 + col;
                int rB = wn * 32 + col;
                v8s a0 = *(const v8s*)&sm.sp.As[rA * 72 + kg * 8];
                v8s a1 = *(const v8s*)&sm.sp.As[(rA + 16) * 72 + kg * 8];
                v8s b0 = *(const v8s*)&sm.sp.Bs[rB * 72 + kg * 8];
                v8s b1 = *(const v8s*)&sm.sp.Bs[(rB + 16) * 72 + kg * 8];
                acc[0][0] = __builtin_amdgcn_mfma_f32_16x16x32_bf16(a0, b0, acc[0][0], 0, 0, 0);
                acc[0][1] = __builtin_amdgcn_mfma_f32_16x16x32_bf16(a0, b1, acc[0][1], 0, 0, 0);
                acc[1][0] = __builtin_amdgcn_mfma_f32_16x16x32_bf16(a1, b0, acc[1][0], 0, 0, 0);
                acc[1][1] = __builtin_amdgcn_mfma_f32_16x16x32_bf16(a1, b1, acc[1][1], 0, 0, 0);
            }
        }
        #pragma unroll
        for (int mi = 0; mi < 2; ++mi)
            #pragma unroll
            for (int ni = 0; ni < 2; ++ni) {
                int mb = m0 + wm * 32 + mi * 16 + quad * 4;
                int nn = n0 + wn * 32 + ni * 16 + col;
                float yv = y2[nn];               // SE scale commuted past the pool
                #pragma unroll
                for (int r = 0; r < 4; ++r)
                    Bt[(size_t)(mb + r) * 2048 + 1024 + nn] = f2bf(acc[mi][ni][r] * yv);
            }
    } else {
        // attention, position p = bx-256, coalesced bf16 xrb rows.
        // val[f] with f = 9*cf+rem == 1024*q + c2 (reference reshape reinterpretation).
        int p = bx - 256;
        int h = p >> 5, w = p & 31;
        #pragma unroll
        for (int rem = 0; rem < 9; ++rem) {
            int dh = rem / 3 - 1, dw = rem % 3 - 1;
            bool ok = ((unsigned)(h + dh) < 32u) && ((unsigned)(w + dw) < 32u);
            const unsigned short* rp = xrb + (size_t)((h + dh) * 32 + (w + dw)) * 1024;
            #pragma unroll
            for (int j = 0; j < 4; ++j) {
                int cf = tid + (j << 8);
                sm.at.val[cf * 9 + rem] = ok ? rp[cf] : (unsigned short)0;
            }
        }
        __syncthreads();
        float ctr[4], vvq[9][4], lg[9];
        #pragma unroll
        for (int j = 0; j < 4; ++j) ctr[j] = bf2f(sm.at.val[(4 * tid + j) * 9 + 4]);
        #pragma unroll
        for (int q = 0; q < 9; ++q) {
            uint2 pk = *(const uint2*)&sm.at.val[(q << 10) + 4 * tid];
            vvq[q][0] = bf2f((unsigned short)(pk.x & 0xffffu));
            vvq[q][1] = bf2f((unsigned short)(pk.x >> 16));
            vvq[q][2] = bf2f((unsigned short)(pk.y & 0xffffu));
            vvq[q][3] = bf2f((unsigned short)(pk.y >> 16));
            lg[q] = ctr[0] * vvq[q][0] + ctr[1] * vvq[q][1]
                  + ctr[2] * vvq[q][2] + ctr[3] * vvq[q][3];
        }
        #pragma unroll
        for (int q = 0; q < 9; ++q) {
            float s = lg[q];
            #pragma unroll
            for (int o = 32; o; o >>= 1) s += __shfl_down(s, o);
            if (lane == 0) sm.at.part[q][wv] = s;
        }
        __syncthreads();
        float a9[9], mx = -3.4e38f;
        #pragma unroll
        for (int q = 0; q < 9; ++q) {
            a9[q] = sm.at.part[q][0] + sm.at.part[q][1] + sm.at.part[q][2] + sm.at.part[q][3];
            mx = fmaxf(mx, a9[q]);
        }
        float se = 0.f;
        #pragma unroll
        for (int q = 0; q < 9; ++q) { a9[q] = __expf(a9[q] - mx); se += a9[q]; }
        float inv = 1.f / se;
        float o4[4] = {0.f, 0.f, 0.f, 0.f};
        #pragma unroll
        for (int q = 0; q < 9; ++q) {
            float a = a9[q] * inv;
            #pragma unroll
            for (int j = 0; j < 4; ++j) o4[j] += a * vvq[q][j];
        }
        uint2 pk;
        pk.x = (unsigned)f2bf(o4[0]) | ((unsigned)f2bf(o4[1]) << 16);
        pk.y = (unsigned)f2bf(o4[2]) | ((unsigned)f2bf(o4[3]) << 16);
        *(uint2*)(Bt + (size_t)p * 2048 + 4 * tid) = pk;
    }
}

// ---------------- K5: main GEMM, double-buffered LDS, BN + ReLU ----------------
__global__ __launch_bounds__(256) void k_main(
    const unsigned short* __restrict__ A, const unsigned short* __restrict__ B,
    float* __restrict__ outF,
    const float* __restrict__ gamma, const float* __restrict__ beta,
    const float* __restrict__ mu, const float* __restrict__ var) {
    __shared__ unsigned short As[2][64 * 72];
    __shared__ unsigned short Bs[2][64 * 72];
    const int K = 2048;
    int tid = threadIdx.x;
    int wv = tid >> 6, lane = tid & 63;
    int wm = wv & 1, wn = wv >> 1;
    int m0 = blockIdx.y << 6, n0 = blockIdx.x << 6;
    int col = lane & 15, quad = lane >> 4;
    int sm = tid >> 2;
    int sg = (tid & 3) * 2;
    v4f acc[2][2];
    #pragma unroll
    for (int i = 0; i < 2; ++i)
        #pragma unroll
        for (int j = 0; j < 2; ++j) acc[i][j] = (v4f){0.f, 0.f, 0.f, 0.f};

    const float4* pa = (const float4*)(A + (size_t)(m0 + sm) * K + sg * 8);
    const float4* pb = (const float4*)(B + (size_t)(n0 + sm) * K + sg * 8);
    float4 ra0 = pa[0], ra1 = pa[1], rb0 = pb[0], rb1 = pb[1];
    *(float4*)&As[0][sm * 72 + sg * 8] = ra0;
    *(float4*)&As[0][sm * 72 + sg * 8 + 8] = ra1;
    *(float4*)&Bs[0][sm * 72 + sg * 8] = rb0;
    *(float4*)&Bs[0][sm * 72 + sg * 8 + 8] = rb1;
    for (int it = 0; it < 32; ++it) {
        __syncthreads();
        int cur = it & 1;
        if (it + 1 < 32) {
            int k0 = (it + 1) << 6;
            pa = (const float4*)(A + (size_t)(m0 + sm) * K + k0 + sg * 8);
            pb = (const float4*)(B + (size_t)(n0 + sm) * K + k0 + sg * 8);
            ra0 = pa[0]; ra1 = pa[1];
            rb0 = pb[0]; rb1 = pb[1];
        }
        #pragma unroll
        for (int ks = 0; ks < 2; ++ks) {
            int kg = ks * 4 + quad;
            int rA = wm * 32 + col;
            int rB = wn * 32 + col;
            v8s a0 = *(const v8s*)&As[cur][rA * 72 + kg * 8];
            v8s a1 = *(const v8s*)&As[cur][(rA + 16) * 72 + kg * 8];
            v8s b0 = *(const v8s*)&Bs[cur][rB * 72 + kg * 8];
            v8s b1 = *(const v8s*)&Bs[cur][(rB + 16) * 72 + kg * 8];
            acc[0][0] = __builtin_amdgcn_mfma_f32_16x16x32_bf16(a0, b0, acc[0][0], 0, 0, 0);
            acc[0][1] = __builtin_amdgcn_mfma_f32_16x16x32_bf16(a0, b1, acc[0][1], 0, 0, 0);
            acc[1][0] = __builtin_amdgcn_mfma_f32_16x16x32_bf16(a1, b0, acc[1][0], 0, 0, 0);
            acc[1][1] = __builtin_amdgcn_mfma_f32_16x16x32_bf16(a1, b1, acc[1][1], 0, 0, 0);
        }
        if (it + 1 < 32) {
            int nxt = cur ^ 1;
            *(float4*)&As[nxt][sm * 72 + sg * 8] = ra0;
            *(float4*)&As[nxt][sm * 72 + sg * 8 + 8] = ra1;
            *(float4*)&Bs[nxt][sm * 72 + sg * 8] = rb0;
            *(float4*)&Bs[nxt][sm * 72 + sg * 8 + 8] = rb1;
        }
    }
    #pragma unroll
    for (int mi = 0; mi < 2; ++mi)
        #pragma unroll
        for (int ni = 0; ni < 2; ++ni) {
            int mb = m0 + wm * 32 + mi * 16 + quad * 4;
            int nn = n0 + wn * 32 + ni * 16 + col;
            #pragma unroll
            for (int r = 0; r < 4; ++r) {
                int mm = mb + r;
                float iv = rsqrtf(var[mm] + 1e-5f);
                float sc = iv * gamma[mm];
                float sh = beta[mm] - mu[mm] * sc;
                outF[((size_t)mm << 10) + nn] = fmaxf(fmaf(acc[mi][ni][r], sc, sh), 0.f);
            }
        }
}

extern "C" void kernel_launch(void* const* d_in, const int* in_sizes, int n_in,
                              void* d_out, int out_size, void* d_ws, size_t ws_size,
                              hipStream_t stream) {
    const float* x     = (const float*)d_in[0];
    const float* w1    = (const float*)d_in[1];
    const float* b1    = (const float*)d_in[2];
    const float* w2    = (const float*)d_in[3];
    const float* b2    = (const float*)d_in[4];
    const float* cw    = (const float*)d_in[5];
    const float* gamma = (const float*)d_in[6];
    const float* beta  = (const float*)d_in[7];
    const float* mu    = (const float*)d_in[8];
    const float* var   = (const float*)d_in[9];
    float* wsf = (float*)d_ws;
    unsigned short* Wb  = (unsigned short*)wsf;                 // 4 MB [1024][2048]
    unsigned short* Bt  = (unsigned short*)(wsf + (1 << 20));   // 4 MB [1024][2048]
    unsigned short* xrb = (unsigned short*)(wsf + (2 << 20));   // 2 MB [p][c]
    float* mean = wsf + (3 << 20);
    float* y2   = mean + 1024;
    float* out  = (float*)d_out;

    dim3 g16(16, 16);
    k_A     <<<256, 256, 0, stream>>>(x, cw, mean, Wb);
    k_se    <<<16, 1024, 0, stream>>>(mean, w1, b1, w2, b2, y2);
    k_prep  <<<g16, 256, 0, stream>>>(x, y2, xrb);
    k_spattn<<<1280, 256, 0, stream>>>(x, xrb, y2, Bt);
    k_main  <<<g16, 256, 0, stream>>>(Wb, Bt, out, gamma, beta, mu, var);
}

// Round 8
// 129.817 us; speedup vs baseline: 2.6848x; 1.0093x over previous
//
#include <hip/hip_runtime.h>
#include <hip/hip_bf16.h>

// 1x1024x32x32: SE block + separable-gaussian spatial pool + 3x3 local softmax
// attention + 1x1 conv/BN/ReLU.  Round 8: 5 launches.
//   k_A     : per-channel mean + Wb=bf16(W) + K2 gaussian table (bf16)
//   k_se    : SE MLP -> y2
//   k_prep  : xrb[p][c] = bf16(sigmoid(x*y2[c]))   (transpose via LDS)
//   k_spattn: blocks 0..255   spatial GEMM, A staged from precomputed K2
//             (no in-loop VALU A-gen), B staged from fp32 x w/ inline bf16,
//             *y2 in epilogue (SE scale commutes past the pool)
//             blocks 256..1279 attention on coalesced xrb rows (bf16 LDS)
//   k_main  : bf16 MFMA GEMM (double-buffered LDS) + BN + ReLU
// Lessons pinned: grid.sync ~60us/sync on 8 XCDs (r5) — never cooperative.
//                 inline-sigmoid attention = 9.4M scattered 4B loads (r6) —
//                 always transpose once, then read rows.

typedef __attribute__((ext_vector_type(8))) short v8s;
typedef __attribute__((ext_vector_type(4))) float v4f;

__device__ __forceinline__ float sigmoidf_(float v) {
    return 1.f / (1.f + __expf(-v));
}
__device__ __forceinline__ unsigned short f2bf(float f) {
    unsigned u = __float_as_uint(f);
    u += 0x7fffu + ((u >> 16) & 1u);
    return (unsigned short)(u >> 16);
}
__device__ __forceinline__ float bf2f(unsigned short s) {
    return __uint_as_float(((unsigned)s) << 16);
}

// ---------------- K1: mean + Wb pack + K2 gaussian table ----------------
__global__ __launch_bounds__(256) void k_A(const float* __restrict__ x,
                                           const float* __restrict__ W,
                                           float* __restrict__ mean,
                                           unsigned short* __restrict__ Wb,
                                           unsigned short* __restrict__ K2) {
    __shared__ float Gs[32][32];
    int tid = threadIdx.x, bx = blockIdx.x;
    int wv = tid >> 6, lane = tid & 63;
    // normalized 1-D gaussian table (cheap, per block)
    {
        int row = tid >> 3, col0 = (tid & 7) << 2;
        float e[4], s = 0.f;
        #pragma unroll
        for (int j = 0; j < 4; ++j) {
            float d = (float)(row - (col0 + j));
            e[j] = __expf(-d * d / 4.5f);
            s += e[j];
        }
        s += __shfl_xor(s, 4, 8);
        s += __shfl_xor(s, 2, 8);
        s += __shfl_xor(s, 1, 8);
        float is = 1.f / s;
        #pragma unroll
        for (int j = 0; j < 4; ++j) Gs[row][col0 + j] = e[j] * is;
    }
    // W pack: 2M elements, 8 coalesced chunks
    #pragma unroll
    for (int k = 0; k < 8; ++k) {
        int e = (k << 18) + (bx << 10) + (tid << 2);
        float4 v = *(const float4*)(W + e);
        uint2 pk;
        pk.x = (unsigned)f2bf(v.x) | ((unsigned)f2bf(v.y) << 16);
        pk.y = (unsigned)f2bf(v.z) | ((unsigned)f2bf(v.w) << 16);
        *(uint2*)(Wb + e) = pk;
    }
    // channel c = 4*bx+wv: mean
    int c = (bx << 2) + wv;
    const float* xp = x + (size_t)c * 1024;
    float s = 0.f;
    #pragma unroll
    for (int j = 0; j < 4; ++j) {
        float4 v = *(const float4*)(xp + (j << 8) + (lane << 2));
        s += v.x + v.y + v.z + v.w;
    }
    #pragma unroll
    for (int o = 32; o; o >>= 1) s += __shfl_down(s, o);
    if (lane == 0) mean[c] = s * (1.f / 1024.f);
    // K2 row p = 4*bx+wv: K2[p][hw] = Gs[p>>5][hw>>5] * Gs[p&31][hw&31]
    __syncthreads();
    {
        int p = (bx << 2) + wv;
        float gr = Gs[p >> 5][lane >> 1];
        const float* gq = &Gs[p & 31][(lane & 1) << 4];
        unsigned pk[8];
        #pragma unroll
        for (int t = 0; t < 8; ++t) {
            float v0 = gr * gq[2 * t];
            float v1 = gr * gq[2 * t + 1];
            pk[t] = (unsigned)f2bf(v0) | ((unsigned)f2bf(v1) << 16);
        }
        unsigned short* dst = K2 + (size_t)p * 1024 + (lane << 4);
        *(uint4*)dst = *(uint4*)&pk[0];
        *(uint4*)(dst + 8) = *(uint4*)&pk[4];
    }
}

// ---------------- K2: SE MLP, 16 blocks x 1024 threads ----------------
__global__ __launch_bounds__(1024) void k_se(const float* __restrict__ mean,
                                             const float* __restrict__ w1,
                                             const float* __restrict__ b1,
                                             const float* __restrict__ w2,
                                             const float* __restrict__ b2,
                                             float* __restrict__ y2) {
    __shared__ float ms[1024];
    __shared__ float y1[64];
    __shared__ float w2t[64 * 65];
    int tid = threadIdx.x;
    int c0 = blockIdx.x << 6;
    ms[tid] = mean[tid];
    #pragma unroll
    for (int i = 0; i < 4; ++i) {
        int idx = tid + (i << 10);
        w2t[(idx >> 6) * 65 + (idx & 63)] = w2[(size_t)c0 * 64 + idx];
    }
    __syncthreads();
    int wv = tid >> 6, lane = tid & 63;
    #pragma unroll
    for (int jj = 0; jj < 4; ++jj) {
        int j = (wv << 2) + jj;
        float s = 0.f;
        #pragma unroll
        for (int kk = 0; kk < 4; ++kk) {
            float4 wv4 = *(const float4*)(w1 + (size_t)j * 1024 + kk * 256 + (lane << 2));
            float4 mv  = *(const float4*)&ms[kk * 256 + (lane << 2)];
            s += wv4.x * mv.x + wv4.y * mv.y + wv4.z * mv.z + wv4.w * mv.w;
        }
        #pragma unroll
        for (int o = 32; o; o >>= 1) s += __shfl_down(s, o);
        if (lane == 0) y1[j] = fmaxf(s + b1[j], 0.f);
    }
    __syncthreads();
    int o = tid >> 4, l = tid & 15;
    float s = 0.f;
    #pragma unroll
    for (int jj = 0; jj < 4; ++jj) s += y1[l + (jj << 4)] * w2t[o * 65 + l + (jj << 4)];
    #pragma unroll
    for (int o2 = 8; o2; o2 >>= 1) s += __shfl_down(s, o2, 16);
    if (l == 0) y2[c0 + o] = sigmoidf_(s + b2[c0 + o]);
}

// ---------------- K3: xrb[p][c] = bf16(sigmoid(x[c][p]*y2[c])) ----------------
__global__ __launch_bounds__(256) void k_prep(const float* __restrict__ x,
                                              const float* __restrict__ y2,
                                              unsigned short* __restrict__ xrb) {
    __shared__ float T[64][65];
    int tid = threadIdx.x;
    int p0 = blockIdx.x << 6, c0 = blockIdx.y << 6;
    #pragma unroll
    for (int i = 0; i < 4; ++i) {
        int idx = tid + (i << 8);
        int row = idx >> 4;
        int col = (idx & 15) << 2;
        float sc = y2[c0 + row];
        float4 v = *(const float4*)(x + (size_t)(c0 + row) * 1024 + p0 + col);
        T[col + 0][row] = sigmoidf_(v.x * sc);
        T[col + 1][row] = sigmoidf_(v.y * sc);
        T[col + 2][row] = sigmoidf_(v.z * sc);
        T[col + 3][row] = sigmoidf_(v.w * sc);
    }
    __syncthreads();
    #pragma unroll
    for (int i = 0; i < 4; ++i) {
        int idx = tid + (i << 8);
        int prow = idx >> 4;
        int cc = (idx & 15) << 2;
        uint2 pk;
        pk.x = (unsigned)f2bf(T[prow][cc + 0]) | ((unsigned)f2bf(T[prow][cc + 1]) << 16);
        pk.y = (unsigned)f2bf(T[prow][cc + 2]) | ((unsigned)f2bf(T[prow][cc + 3]) << 16);
        *(uint2*)(xrb + (size_t)(p0 + prow) * 1024 + c0 + cc) = pk;
    }
}

// ---------------- K4: fused spatial GEMM + attention ----------------
union __align__(16) SMem {
    struct { unsigned short As[64 * 72]; unsigned short Bs[64 * 72]; } sp;  // 18 KB
    struct { unsigned short val[9216]; float part[9][4]; } at;              // 18.6 KB
};

__global__ __launch_bounds__(256) void k_spattn(const float* __restrict__ x,
                                                const unsigned short* __restrict__ xrb,
                                                const unsigned short* __restrict__ K2,
                                                const float* __restrict__ y2,
                                                unsigned short* __restrict__ Bt) {
    __shared__ SMem sm;
    int tid = threadIdx.x;
    int bx = blockIdx.x;
    int wv = tid >> 6, lane = tid & 63;
    if (bx < 256) {
        // spatial GEMM: Bt[p][1024+c] = y2[c] * sum_hw K2[p][hw]*bf16(x[c][hw])
        int wm = wv & 1, wn = wv >> 1;
        int m0 = (bx >> 4) << 6, n0 = (bx & 15) << 6;
        int col = lane & 15, quad = lane >> 4;
        int smi = tid >> 2;
        int sg = (tid & 3) * 2;
        v4f acc[2][2];
        #pragma unroll
        for (int i = 0; i < 2; ++i)
            #pragma unroll
            for (int j = 0; j < 2; ++j) acc[i][j] = (v4f){0.f, 0.f, 0.f, 0.f};
        const float4* pa = (const float4*)(K2 + (size_t)(m0 + smi) * 1024 + sg * 8);
        const float4* pb = (const float4*)(x + (size_t)(n0 + smi) * 1024 + sg * 8);
        float4 ka0 = pa[0], ka1 = pa[1];
        float4 xa0 = pb[0], xa1 = pb[1], xa2 = pb[2], xa3 = pb[3];
        for (int it = 0; it < 16; ++it) {
            __syncthreads();
            *(float4*)&sm.sp.As[smi * 72 + sg * 8] = ka0;
            *(float4*)&sm.sp.As[smi * 72 + sg * 8 + 8] = ka1;
            uint4 pkb0, pkb1;
            pkb0.x = (unsigned)f2bf(xa0.x) | ((unsigned)f2bf(xa0.y) << 16);
            pkb0.y = (unsigned)f2bf(xa0.z) | ((unsigned)f2bf(xa0.w) << 16);
            pkb0.z = (unsigned)f2bf(xa1.x) | ((unsigned)f2bf(xa1.y) << 16);
            pkb0.w = (unsigned)f2bf(xa1.z) | ((unsigned)f2bf(xa1.w) << 16);
            pkb1.x = (unsigned)f2bf(xa2.x) | ((unsigned)f2bf(xa2.y) << 16);
            pkb1.y = (unsigned)f2bf(xa2.z) | ((unsigned)f2bf(xa2.w) << 16);
            pkb1.z = (unsigned)f2bf(xa3.x) | ((unsigned)f2bf(xa3.y) << 16);
            pkb1.w = (unsigned)f2bf(xa3.z) | ((unsigned)f2bf(xa3.w) << 16);
            *(uint4*)&sm.sp.Bs[smi * 72 + sg * 8] = pkb0;
            *(uint4*)&sm.sp.Bs[smi * 72 + sg * 8 + 8] = pkb1;
            __syncthreads();
            if (it + 1 < 16) {
                int k0 = (it + 1) << 6;
                pa = (const float4*)(K2 + (size_t)(m0 + smi) * 1024 + k0 + sg * 8);
                pb = (const float4*)(x + (size_t)(n0 + smi) * 1024 + k0 + sg * 8);
                ka0 = pa[0]; ka1 = pa[1];
                xa0 = pb[0]; xa1 = pb[1]; xa2 = pb[2]; xa3 = pb[3];
            }
            #pragma unroll
            for (int ks = 0; ks < 2; ++ks) {
                int kg = ks * 4 + quad;
                int rA = wm * 32 + col;
                int rB = wn * 32 + col;
                v8s a0 = *(const v8s*)&sm.sp.As[rA * 72 + kg * 8];
                v8s a1 = *(const v8s*)&sm.sp.As[(rA + 16) * 72 + kg * 8];
                v8s b0 = *(const v8s*)&sm.sp.Bs[rB * 72 + kg * 8];
                v8s b1 = *(const v8s*)&sm.sp.Bs[(rB + 16) * 72 + kg * 8];
                acc[0][0] = __builtin_amdgcn_mfma_f32_16x16x32_bf16(a0, b0, acc[0][0], 0, 0, 0);
                acc[0][1] = __builtin_amdgcn_mfma_f32_16x16x32_bf16(a0, b1, acc[0][1], 0, 0, 0);
                acc[1][0] = __builtin_amdgcn_mfma_f32_16x16x32_bf16(a1, b0, acc[1][0], 0, 0, 0);
                acc[1][1] = __builtin_amdgcn_mfma_f32_16x16x32_bf16(a1, b1, acc[1][1], 0, 0, 0);
            }
        }
        #pragma unroll
        for (int mi = 0; mi < 2; ++mi)
            #pragma unroll
            for (int ni = 0; ni < 2; ++ni) {
                int mb = m0 + wm * 32 + mi * 16 + quad * 4;
                int nn = n0 + wn * 32 + ni * 16 + col;
                float yv = y2[nn];               // SE scale commuted past the pool
                #pragma unroll
                for (int r = 0; r < 4; ++r)
                    Bt[(size_t)(mb + r) * 2048 + 1024 + nn] = f2bf(acc[mi][ni][r] * yv);
            }
    } else {
        // attention, position p = bx-256, coalesced bf16 xrb rows.
        // val[f] with f = 9*cf+rem == 1024*q + c2 (reference reshape reinterpretation).
        int p = bx - 256;
        int h = p >> 5, w = p & 31;
        #pragma unroll
        for (int rem = 0; rem < 9; ++rem) {
            int dh = rem / 3 - 1, dw = rem % 3 - 1;
            bool ok = ((unsigned)(h + dh) < 32u) && ((unsigned)(w + dw) < 32u);
            const unsigned short* rp = xrb + (size_t)((h + dh) * 32 + (w + dw)) * 1024;
            #pragma unroll
            for (int j = 0; j < 4; ++j) {
                int cf = tid + (j << 8);
                sm.at.val[cf * 9 + rem] = ok ? rp[cf] : (unsigned short)0;
            }
        }
        __syncthreads();
        float ctr[4], vvq[9][4], lg[9];
        #pragma unroll
        for (int j = 0; j < 4; ++j) ctr[j] = bf2f(sm.at.val[(4 * tid + j) * 9 + 4]);
        #pragma unroll
        for (int q = 0; q < 9; ++q) {
            uint2 pk = *(const uint2*)&sm.at.val[(q << 10) + 4 * tid];
            vvq[q][0] = bf2f((unsigned short)(pk.x & 0xffffu));
            vvq[q][1] = bf2f((unsigned short)(pk.x >> 16));
            vvq[q][2] = bf2f((unsigned short)(pk.y & 0xffffu));
            vvq[q][3] = bf2f((unsigned short)(pk.y >> 16));
            lg[q] = ctr[0] * vvq[q][0] + ctr[1] * vvq[q][1]
                  + ctr[2] * vvq[q][2] + ctr[3] * vvq[q][3];
        }
        #pragma unroll
        for (int q = 0; q < 9; ++q) {
            float s = lg[q];
            #pragma unroll
            for (int o = 32; o; o >>= 1) s += __shfl_down(s, o);
            if (lane == 0) sm.at.part[q][wv] = s;
        }
        __syncthreads();
        float a9[9], mx = -3.4e38f;
        #pragma unroll
        for (int q = 0; q < 9; ++q) {
            a9[q] = sm.at.part[q][0] + sm.at.part[q][1] + sm.at.part[q][2] + sm.at.part[q][3];
            mx = fmaxf(mx, a9[q]);
        }
        float se = 0.f;
        #pragma unroll
        for (int q = 0; q < 9; ++q) { a9[q] = __expf(a9[q] - mx); se += a9[q]; }
        float inv = 1.f / se;
        float o4[4] = {0.f, 0.f, 0.f, 0.f};
        #pragma unroll
        for (int q = 0; q < 9; ++q) {
            float a = a9[q] * inv;
            #pragma unroll
            for (int j = 0; j < 4; ++j) o4[j] += a * vvq[q][j];
        }
        uint2 pk;
        pk.x = (unsigned)f2bf(o4[0]) | ((unsigned)f2bf(o4[1]) << 16);
        pk.y = (unsigned)f2bf(o4[2]) | ((unsigned)f2bf(o4[3]) << 16);
        *(uint2*)(Bt + (size_t)p * 2048 + 4 * tid) = pk;
    }
}

// ---------------- K5: main GEMM, double-buffered LDS, BN + ReLU ----------------
__global__ __launch_bounds__(256) void k_main(
    const unsigned short* __restrict__ A, const unsigned short* __restrict__ B,
    float* __restrict__ outF,
    const float* __restrict__ gamma, const float* __restrict__ beta,
    const float* __restrict__ mu, const float* __restrict__ var) {
    __shared__ unsigned short As[2][64 * 72];
    __shared__ unsigned short Bs[2][64 * 72];
    const int K = 2048;
    int tid = threadIdx.x;
    int wv = tid >> 6, lane = tid & 63;
    int wm = wv & 1, wn = wv >> 1;
    int m0 = blockIdx.y << 6, n0 = blockIdx.x << 6;
    int col = lane & 15, quad = lane >> 4;
    int sm = tid >> 2;
    int sg = (tid & 3) * 2;
    v4f acc[2][2];
    #pragma unroll
    for (int i = 0; i < 2; ++i)
        #pragma unroll
        for (int j = 0; j < 2; ++j) acc[i][j] = (v4f){0.f, 0.f, 0.f, 0.f};

    const float4* pa = (const float4*)(A + (size_t)(m0 + sm) * K + sg * 8);
    const float4* pb = (const float4*)(B + (size_t)(n0 + sm) * K + sg * 8);
    float4 ra0 = pa[0], ra1 = pa[1], rb0 = pb[0], rb1 = pb[1];
    *(float4*)&As[0][sm * 72 + sg * 8] = ra0;
    *(float4*)&As[0][sm * 72 + sg * 8 + 8] = ra1;
    *(float4*)&Bs[0][sm * 72 + sg * 8] = rb0;
    *(float4*)&Bs[0][sm * 72 + sg * 8 + 8] = rb1;
    for (int it = 0; it < 32; ++it) {
        __syncthreads();
        int cur = it & 1;
        if (it + 1 < 32) {
            int k0 = (it + 1) << 6;
            pa = (const float4*)(A + (size_t)(m0 + sm) * K + k0 + sg * 8);
            pb = (const float4*)(B + (size_t)(n0 + sm) * K + k0 + sg * 8);
            ra0 = pa[0]; ra1 = pa[1];
            rb0 = pb[0]; rb1 = pb[1];
        }
        #pragma unroll
        for (int ks = 0; ks < 2; ++ks) {
            int kg = ks * 4 + quad;
            int rA = wm * 32 + col;
            int rB = wn * 32 + col;
            v8s a0 = *(const v8s*)&As[cur][rA * 72 + kg * 8];
            v8s a1 = *(const v8s*)&As[cur][(rA + 16) * 72 + kg * 8];
            v8s b0 = *(const v8s*)&Bs[cur][rB * 72 + kg * 8];
            v8s b1 = *(const v8s*)&Bs[cur][(rB + 16) * 72 + kg * 8];
            acc[0][0] = __builtin_amdgcn_mfma_f32_16x16x32_bf16(a0, b0, acc[0][0], 0, 0, 0);
            acc[0][1] = __builtin_amdgcn_mfma_f32_16x16x32_bf16(a0, b1, acc[0][1], 0, 0, 0);
            acc[1][0] = __builtin_amdgcn_mfma_f32_16x16x32_bf16(a1, b0, acc[1][0], 0, 0, 0);
            acc[1][1] = __builtin_amdgcn_mfma_f32_16x16x32_bf16(a1, b1, acc[1][1], 0, 0, 0);
        }
        if (it + 1 < 32) {
            int nxt = cur ^ 1;
            *(float4*)&As[nxt][sm * 72 + sg * 8] = ra0;
            *(float4*)&As[nxt][sm * 72 + sg * 8 + 8] = ra1;
            *(float4*)&Bs[nxt][sm * 72 + sg * 8] = rb0;
            *(float4*)&Bs[nxt][sm * 72 + sg * 8 + 8] = rb1;
        }
    }
    #pragma unroll
    for (int mi = 0; mi < 2; ++mi)
        #pragma unroll
        for (int ni = 0; ni < 2; ++ni) {
            int mb = m0 + wm * 32 + mi * 16 + quad * 4;
            int nn = n0 + wn * 32 + ni * 16 + col;
            #pragma unroll
            for (int r = 0; r < 4; ++r) {
                int mm = mb + r;
                float iv = rsqrtf(var[mm] + 1e-5f);
                float sc = iv * gamma[mm];
                float sh = beta[mm] - mu[mm] * sc;
                outF[((size_t)mm << 10) + nn] = fmaxf(fmaf(acc[mi][ni][r], sc, sh), 0.f);
            }
        }
}

extern "C" void kernel_launch(void* const* d_in, const int* in_sizes, int n_in,
                              void* d_out, int out_size, void* d_ws, size_t ws_size,
                              hipStream_t stream) {
    const float* x     = (const float*)d_in[0];
    const float* w1    = (const float*)d_in[1];
    const float* b1    = (const float*)d_in[2];
    const float* w2    = (const float*)d_in[3];
    const float* b2    = (const float*)d_in[4];
    const float* cw    = (const float*)d_in[5];
    const float* gamma = (const float*)d_in[6];
    const float* beta  = (const float*)d_in[7];
    const float* mu    = (const float*)d_in[8];
    const float* var   = (const float*)d_in[9];
    float* wsf = (float*)d_ws;
    unsigned short* Wb  = (unsigned short*)wsf;                 // 4 MB [1024][2048]
    unsigned short* Bt  = (unsigned short*)(wsf + (1 << 20));   // 4 MB [1024][2048]
    unsigned short* xrb = (unsigned short*)(wsf + (2 << 20));   // 2 MB [p][c]
    unsigned short* K2  = (unsigned short*)(wsf + (2 << 20) + (1 << 19)); // 2 MB [p][hw]
    float* mean = wsf + (3 << 20);
    float* y2   = mean + 1024;
    float* out  = (float*)d_out;

    dim3 g16(16, 16);
    k_A     <<<256, 256, 0, stream>>>(x, cw, mean, Wb, K2);
    k_se    <<<16, 1024, 0, stream>>>(mean, w1, b1, w2, b2, y2);
    k_prep  <<<g16, 256, 0, stream>>>(x, y2, xrb);
    k_spattn<<<1280, 256, 0, stream>>>(x, xrb, K2, y2, Bt);
    k_main  <<<g16, 256, 0, stream>>>(Wb, Bt, out, gamma, beta, mu, var);
}